// Round 1
// baseline (501.969 us; speedup 1.0000x reference)
//
#include <hip/hip_runtime.h>
#include <hip/hip_bf16.h>
#include <math.h>

typedef __bf16 bf16;
typedef __bf16 v8bf __attribute__((ext_vector_type(8)));
typedef __bf16 v4bfv __attribute__((ext_vector_type(4)));
typedef float  v4f  __attribute__((ext_vector_type(4)));

#define B_   128
#define KK_  49
#define D_   512
#define E_   256
#define V_   10000
#define T_   20
#define NG_  2048   // 4*D
#define XK_  768    // E+D
#define VPAD 10112  // 79*128 (Wp rows padded)
#define NP_  128    // padded small-N
#define NBLK 64     // flags alloc sizing (2048 ints)
#define LGRID 256   // lstm_persist grid (1 block/CU, co-resident)

// flag-array layout (ints, all zeroed by prep each launch):
//   [0 .. 1023]   step flags: slot s at s*32 (32 slots, line-separated)
//   [1024..1039]  per-XCD registration counters
//   [1040..1055]  per-XCD ready state (0=wait, 1=run, 2=skip)
//   [1056]        leader (0=none, else xcd+1)
//   [1057]        done
#define FLG_CNT    1024
#define FLG_READY  1040
#define FLG_LEADER 1056
#define FLG_DONE   1057

#define GLOAD_LDS16(gp, lp) \
    __builtin_amdgcn_global_load_lds((const __attribute__((address_space(1))) void*)(gp), \
                                     (__attribute__((address_space(3))) void*)(lp), 16, 0, 0)

__device__ inline v4bfv cvt4(float4 v) {
    v4bfv o; o[0] = (bf16)v.x; o[1] = (bf16)v.y; o[2] = (bf16)v.z; o[3] = (bf16)v.w;
    return o;
}

// ---------------------------------------------------------------------------
// Prep: fp32->bf16 conversions, padding, gather of LSTM input rows, packed
// init weights/biases, barrier-flag zeroing.
// ---------------------------------------------------------------------------
__global__ void prep_kernel(
    const float* __restrict__ spatial, const float* __restrict__ gfeat,
    const int* __restrict__ caps, const float* __restrict__ emb,
    const float* __restrict__ W_init_h, const float* __restrict__ b_init_h,
    const float* __restrict__ W_init_m, const float* __restrict__ b_init_m,
    const float* __restrict__ W_ih, const float* __restrict__ b_ih,
    const float* __restrict__ W_hh, const float* __restrict__ b_hh,
    const float* __restrict__ Wv, const float* __restrict__ bv,
    const float* __restrict__ Wg, const float* __restrict__ bg,
    const float* __restrict__ Wp,
    bf16* __restrict__ Wp_b, bf16* __restrict__ Whh_b, bf16* __restrict__ Wih_b,
    bf16* __restrict__ Xin_b, bf16* __restrict__ Sp_b,
    bf16* __restrict__ Wv_b, bf16* __restrict__ Wg_b,
    bf16* __restrict__ Winit2_b, bf16* __restrict__ Gf_b,
    float* __restrict__ bias_comb, float* __restrict__ bias_init,
    float* __restrict__ bv_pad, float* __restrict__ bg_pad,
    int* __restrict__ flags)
{
    const int stride = gridDim.x * blockDim.x;
    const int tid0 = blockIdx.x * blockDim.x + threadIdx.x;
    const float4 z4 = make_float4(0.f, 0.f, 0.f, 0.f);

    for (int i = tid0; i < NBLK * 32; i += stride) flags[i] = 0;   // covers all flag fields

    for (int i4 = tid0; i4 < VPAD * D_ / 4; i4 += stride) {
        int row = i4 >> 7;
        float4 v = (row < V_) ? ((const float4*)Wp)[i4] : z4;
        ((v4bfv*)Wp_b)[i4] = cvt4(v);
    }
    for (int i4 = tid0; i4 < NG_ * D_ / 4; i4 += stride)
        ((v4bfv*)Whh_b)[i4] = cvt4(((const float4*)W_hh)[i4]);
    for (int i4 = tid0; i4 < NG_ * XK_ / 4; i4 += stride)
        ((v4bfv*)Wih_b)[i4] = cvt4(((const float4*)W_ih)[i4]);
    // Xin rows r = t*128+b : [emb[captions[b,t]], global_feats[b]]
    for (int i4 = tid0; i4 < T_ * B_ * XK_ / 4; i4 += stride) {
        int r = i4 / (XK_ / 4), c4 = i4 - r * (XK_ / 4);
        int c = c4 * 4;
        int t = r >> 7, b = r & 127;
        float4 v;
        if (c < E_) v = *(const float4*)&emb[(long)caps[b * T_ + t] * E_ + c];
        else        v = *(const float4*)&gfeat[(long)b * D_ + (c - E_)];
        ((v4bfv*)Xin_b)[i4] = cvt4(v);
    }
    for (int i4 = tid0; i4 < B_ * KK_ * D_ / 4; i4 += stride)
        ((v4bfv*)Sp_b)[i4] = cvt4(((const float4*)spatial)[i4]);
    for (int i4 = tid0; i4 < NP_ * D_ / 4; i4 += stride) {
        int row = i4 >> 7;
        ((v4bfv*)Wv_b)[i4] = cvt4((row < KK_) ? ((const float4*)Wv)[i4] : z4);
        ((v4bfv*)Wg_b)[i4] = cvt4((row < KK_) ? ((const float4*)Wg)[i4] : z4);
    }
    // packed [W_init_h; W_init_m]  (1024 x 512)
    for (int i4 = tid0; i4 < 2 * D_ * D_ / 4; i4 += stride) {
        int row = i4 >> 7;
        float4 v = (row < D_) ? ((const float4*)W_init_h)[i4]
                              : ((const float4*)W_init_m)[i4 - D_ * (D_ / 4)];
        ((v4bfv*)Winit2_b)[i4] = cvt4(v);
    }
    for (int i4 = tid0; i4 < B_ * D_ / 4; i4 += stride)
        ((v4bfv*)Gf_b)[i4] = cvt4(((const float4*)gfeat)[i4]);
    for (int i = tid0; i < NG_; i += stride) bias_comb[i] = b_ih[i] + b_hh[i];
    for (int i = tid0; i < 2 * D_; i += stride)
        bias_init[i] = (i < D_) ? b_init_h[i] : b_init_m[i - D_];
    for (int i = tid0; i < NP_; i += stride) {
        bv_pad[i] = (i < KK_) ? bv[i] : 0.f;
        bg_pad[i] = (i < KK_) ? bg[i] : 0.f;
    }
}

// ---------------------------------------------------------------------------
// Generic bf16 MFMA GEMM, BK=64: C[M,N] = A[M,K] @ Bm[N,K]^T + bias[n]
// 128x128 tile, 4 waves, each 64x64. blockIdx.x = m-tile (fastest).
// __launch_bounds__(256,4): request 4 blocks/CU (VGPR<=128; now 72).
// OUTMODE: 0=f32, 2=logits (masked f32, n<n_real, stride out_stride),
//          3=split: n<D_ -> bf16 Cout[m*D_+n], else f32 Cout2[m*D_+n-D_]
// ---------------------------------------------------------------------------
template <int OUTMODE>
__global__ __launch_bounds__(256, 4) void gemm_bt(
    const bf16* __restrict__ A, const bf16* __restrict__ Bm,
    const float* __restrict__ bias, void* __restrict__ Cout, void* __restrict__ Cout2,
    int M, int N, int K, int out_stride, int n_real, const int* __restrict__ lengths)
{
    __shared__ bf16 As[2 * 128 * 32];
    __shared__ bf16 Bs[2 * 128 * 32];
    const int m0 = blockIdx.x * 128, n0 = blockIdx.y * 128;
    const int tid = threadIdx.x;
    const int w = tid >> 6, l = tid & 63;
    const int wm = (w >> 1) * 64, wn = (w & 1) * 64;
    const int lr = l & 15, lq = l >> 4;

    v4f acc[4][4] = {};

    for (int k0 = 0; k0 < K; k0 += 64) {
        __syncthreads();
        #pragma unroll
        for (int c = 0; c < 4; c++) {
            int u = c * 256 + tid;
            int h = u >> 9, v = u & 511;
            int row = v >> 2, kc = (v & 3) * 8;
            int u0 = c * 256 + (tid & ~63);
            GLOAD_LDS16(&A[(long)(m0 + row) * K + k0 + h * 32 + kc], &As[u0 * 8]);
            GLOAD_LDS16(&Bm[(long)(n0 + row) * K + k0 + h * 32 + kc], &Bs[u0 * 8]);
        }
        __syncthreads();
        #pragma unroll
        for (int h = 0; h < 2; h++) {
            v8bf af[4], bfv[4];
            #pragma unroll
            for (int s = 0; s < 4; s++) {
                af[s]  = *(const v8bf*)&As[h * 4096 + (wm + s * 16 + lr) * 32 + lq * 8];
                bfv[s] = *(const v8bf*)&Bs[h * 4096 + (wn + s * 16 + lr) * 32 + lq * 8];
            }
            #pragma unroll
            for (int i = 0; i < 4; i++)
                #pragma unroll
                for (int j = 0; j < 4; j++)
                    acc[i][j] = __builtin_amdgcn_mfma_f32_16x16x32_bf16(af[i], bfv[j], acc[i][j], 0, 0, 0);
        }
    }

    #pragma unroll
    for (int i = 0; i < 4; i++)
        #pragma unroll
        for (int j = 0; j < 4; j++)
            #pragma unroll
            for (int r = 0; r < 4; r++) {
                int m = m0 + wm + i * 16 + lq * 4 + r;
                int n = n0 + wn + j * 16 + lr;
                float v = acc[i][j][r];
                if (OUTMODE == 2) {
                    if (n < n_real) {
                        int t = m % T_, b = m / T_;
                        float o = (t < lengths[b]) ? (v + bias[n]) : 0.f;
                        ((float*)Cout)[(long)m * out_stride + n] = o;
                    }
                } else if (OUTMODE == 3) {
                    if (n < D_) ((bf16*)Cout)[(long)m * D_ + n] = (bf16)(v + bias[n]);
                    else ((float*)Cout2)[(long)m * D_ + n - D_] = v + bias[n];
                } else {
                    ((float*)Cout)[(long)m * out_stride + n] = v + bias[n];
                }
            }
}

// ---------------------------------------------------------------------------
// Persistent LSTM recurrence, XCD-LOCAL exchange (no per-step threadfence).
//
// Launch LGRID=256 blocks (133 KB LDS -> 1 block/CU -> all co-resident).
// Each block reads HW_REG_XCC_ID (m09-verified) and grabs a per-XCD slot via
// atomicAdd. The first XCD to collect 32 blocks wins a CAS and becomes the
// SINGLE runner group (pigeonhole: 256 blocks / 8 XCDs guarantees a winner);
// losing complete groups get ready=2 and exit; starved incomplete groups spin
// on (ready | done) and exit when the runner sets done -> no hang under ANY
// block->XCD mapping.
//
// Runner group: 32 co-XCD blocks = 2 row-halves (rh) x 16 d-slices (dt) of 32
// cols. W_hh slice (128 rows x 512) lives in LDS for all T steps. Per step:
// gates = H[t] @ Whh_slice^T (128 MFMA/wave), elementwise LSTM, h_new stored
// with NONTEMPORAL stores (keeps producer L1 clean -> consumers' L1-miss reads
// hit the shared XCD L2 with fresh data). Release = the vmcnt(0) drain
// __syncthreads already performs (stores are in the shared L2 after the
// barrier); then a relaxed agent flag store. Acquire = flag poll only -- no
// buffer_wbl2/buffer_inv since ALL data producers/consumers share one L2.
// Each row-half polls only its 16 producer flags.
// ---------------------------------------------------------------------------
__global__ __launch_bounds__(256) void lstm_persist(
    bf16* __restrict__ Hb16, const bf16* __restrict__ Whh_b,
    const float* __restrict__ Xpre, const float* __restrict__ mbuf,
    const int* __restrict__ lengths, int* __restrict__ flags)
{
    __shared__ bf16 Bl[128][520];   // 133,120 B -> 1 block/CU
    __shared__ int s_info[2];
    const int tid = threadIdx.x;

    if (tid == 0) {
        int xcd;
        asm volatile("s_getreg_b32 %0, hwreg(HW_REG_XCC_ID)" : "=s"(xcd));
        xcd &= 15;
        int slot = __hip_atomic_fetch_add(&flags[FLG_CNT + xcd], 1,
                                          __ATOMIC_RELAXED, __HIP_MEMORY_SCOPE_AGENT);
        if (slot == 31) {   // 32nd member: try to claim the runner role for this XCD
            int exp = 0;
            bool win = __hip_atomic_compare_exchange_strong(
                &flags[FLG_LEADER], &exp, xcd + 1,
                __ATOMIC_RELAXED, __ATOMIC_RELAXED, __HIP_MEMORY_SCOPE_AGENT);
            __hip_atomic_store(&flags[FLG_READY + xcd], win ? 1 : 2,
                               __ATOMIC_RELAXED, __HIP_MEMORY_SCOPE_AGENT);
        }
        int st;
        if (slot < 32) {
            int dn;
            do {
                st = __hip_atomic_load(&flags[FLG_READY + xcd],
                                       __ATOMIC_RELAXED, __HIP_MEMORY_SCOPE_AGENT);
                dn = __hip_atomic_load(&flags[FLG_DONE],
                                       __ATOMIC_RELAXED, __HIP_MEMORY_SCOPE_AGENT);
            } while (st == 0 && dn == 0);
            if (st == 0) st = 2;          // starved group released by runner's done
        } else st = 2;                    // surplus block on a full XCD
        s_info[0] = st;
        s_info[1] = slot;
    }
    __syncthreads();
    if (s_info[0] != 1) return;

    const int slot = s_info[1];
    const int w = tid >> 6, l = tid & 63;
    const int lr = l & 15, lq = l >> 4;
    const int rh = slot & 1;              // row-half: batch rows [rh*64, rh*64+64)
    const int d0v = (slot >> 1) * 32;     // 32 d-cols
    const int b0 = rh * 64;

    // stage W_hh slice: Bl[j] <- Whh row (j>>5)*512 + d0v + (j&31), j in [0,128)
    for (int u = tid; u < 128 * 64; u += 256) {
        int row = u >> 6, kc = (u & 63) * 8;
        int g = row >> 5, dd = row & 31;
        *(v8bf*)&Bl[row][kc] = *(const v8bf*)&Whh_b[(long)(g * D_ + d0v + dd) * D_ + kc];
    }

    // per-thread state: r=0..3 -> b = b0 + w*16 + lq*4 + r ; dh=0..1 -> d = d0v + dh*16 + lr
    const int brow = b0 + w * 16 + lq * 4;
    float m_st[4][2], h_st[4][2], xpf[4][2][4];
    int lenr[4];
    #pragma unroll
    for (int r = 0; r < 4; r++) {
        int b = brow + r;
        lenr[r] = lengths[b];
        #pragma unroll
        for (int dh = 0; dh < 2; dh++) {
            int d = d0v + dh * 16 + lr;
            m_st[r][dh] = mbuf[(long)b * D_ + d];
            h_st[r][dh] = (float)Hb16[(long)b * D_ + d];
            #pragma unroll
            for (int g = 0; g < 4; g++)
                xpf[r][dh][g] = Xpre[(long)b * NG_ + g * D_ + d];
        }
    }
    __syncthreads();

    for (int t = 0; t < T_; t++) {
        // gates = H[t] @ Whh_slice^T : wave w owns m-rows b0+w*16..+15
        // acc[nt] <-> gate g = nt>>1, d = d0v + (nt&1)*16 + lr
        const bf16* Arow = Hb16 + (long)t * B_ * D_ + (long)(b0 + w * 16 + lr) * D_;
        v4f acc[8] = {};
        #pragma unroll
        for (int kk = 0; kk < 16; kk++) {
            v8bf a = *(const v8bf*)&Arow[kk * 32 + lq * 8];
            #pragma unroll
            for (int nt = 0; nt < 8; nt++) {
                v8bf bv = *(const v8bf*)&Bl[nt * 16 + lr][kk * 32 + lq * 8];
                acc[nt] = __builtin_amdgcn_mfma_f32_16x16x32_bf16(a, bv, acc[nt], 0, 0, 0);
            }
        }

        bf16* hn = Hb16 + (long)(t + 1) * B_ * D_;
        #pragma unroll
        for (int r = 0; r < 4; r++) {
            int b = brow + r;
            bool active = t < lenr[r];
            #pragma unroll
            for (int dh = 0; dh < 2; dh++) {
                float gi = acc[0 + dh][r] + xpf[r][dh][0];
                float gf = acc[2 + dh][r] + xpf[r][dh][1];
                float gc = acc[4 + dh][r] + xpf[r][dh][2];
                float go = acc[6 + dh][r] + xpf[r][dh][3];
                gi = 1.f / (1.f + expf(-gi));
                gf = 1.f / (1.f + expf(-gf));
                gc = tanhf(gc);
                go = 1.f / (1.f + expf(-go));
                float m_new = gf * m_st[r][dh] + gi * gc;
                float h_new = go * tanhf(m_new);
                m_st[r][dh] = active ? m_new : m_st[r][dh];
                h_st[r][dh] = active ? h_new : h_st[r][dh];
                bf16 hv = (bf16)h_st[r][dh];
                // nontemporal: no L1 allocate -> no stale partial lines anywhere
                __builtin_nontemporal_store(__builtin_bit_cast(short, hv),
                    (short*)&hn[(long)b * D_ + d0v + dh * 16 + lr]);
            }
        }

        if (t + 1 < T_) {
            __syncthreads();   // per-wave vmcnt(0) drain -> h-stores in shared XCD L2
            if (tid == 0)
                __hip_atomic_store(&flags[slot * 32], t + 1,
                                   __ATOMIC_RELAXED, __HIP_MEMORY_SCOPE_AGENT);
            // prefetch next step's Xpre while peers arrive
            #pragma unroll
            for (int r = 0; r < 4; r++) {
                int b = brow + r;
                #pragma unroll
                for (int dh = 0; dh < 2; dh++)
                    #pragma unroll
                    for (int g = 0; g < 4; g++)
                        xpf[r][dh][g] = Xpre[(long)(t + 1) * B_ * NG_ + (long)b * NG_
                                             + g * D_ + d0v + dh * 16 + lr];
            }
            if (w == 0) {      // lane i (<16) polls producer slot 2*i+rh (same row-half)
                int need = t + 1, v = need;
                do {
                    if (l < 16)
                        v = __hip_atomic_load(&flags[(2 * l + rh) * 32],
                                              __ATOMIC_RELAXED, __HIP_MEMORY_SCOPE_AGENT);
                } while (__any(v < need));
            }
            __syncthreads();
        }
    }

    if (slot == 0 && tid == 0)   // release any starved incomplete groups
        __hip_atomic_store(&flags[FLG_DONE], 1, __ATOMIC_RELAXED, __HIP_MEMORY_SCOPE_AGENT);
}

// ---------------------------------------------------------------------------
// Attention + context. 4 waves/block share b (Vproj tile staged in LDS once);
// wave owns one t. ctx[b*T+t] = softmax_k(wh.tanh(Vproj+Wg h))@spatial[b]+h_t.
// ---------------------------------------------------------------------------
__global__ __launch_bounds__(256) void attn_kernel(
    const bf16* __restrict__ Hb16, const float* __restrict__ g_all,
    const float* __restrict__ Vproj, const float* __restrict__ wh,
    const bf16* __restrict__ Sp_b, bf16* __restrict__ ctx)
{
    const int w = threadIdx.x >> 6, l = threadIdx.x & 63;
    const int b = blockIdx.x / 5, tg = blockIdx.x % 5;
    const int t = tg * 4 + w;
    const int r = t * 128 + b;
    __shared__ float svp[KK_][53];
    __shared__ float sg[4][64], sal[4][64], swh[64];

    for (int p = threadIdx.x; p < KK_ * 64; p += 256) {
        int k = p >> 6, j = p & 63;
        if (j < KK_) svp[k][j] = Vproj[((long)b * KK_ + k) * NP_ + j];
    }
    if (w == 0) swh[l] = (l < KK_) ? wh[l] : 0.f;
    sg[w][l] = (l < KK_) ? g_all[(long)r * NP_ + l] : 0.f;
    __syncthreads();

    float z = -1e30f;
    if (l < KK_) {
        float a = 0.f;
        for (int j = 0; j < KK_; j++)
            a += swh[j] * tanhf(svp[l][j] + sg[w][j]);
        z = a;
    }
    float mx = z;
    #pragma unroll
    for (int o = 32; o > 0; o >>= 1) mx = fmaxf(mx, __shfl_xor(mx, o));
    float e = (l < KK_) ? expf(z - mx) : 0.f;
    float sm = e;
    #pragma unroll
    for (int o = 32; o > 0; o >>= 1) sm += __shfl_xor(sm, o);
    sal[w][l] = e / sm;
    __syncthreads();

    const bf16* hrow = Hb16 + (long)(t + 1) * B_ * D_ + (long)b * D_;
    const bf16* sp = Sp_b + (long)b * KK_ * D_;
    bf16* crow = ctx + (long)(b * T_ + t) * D_;
    v8bf hro = *(const v8bf*)&hrow[l * 8];
    float c[8] = {};
    for (int k = 0; k < KK_; k++) {
        v8bf s8 = *(const v8bf*)&sp[k * D_ + l * 8];
        float al = sal[w][k];
        #pragma unroll
        for (int e2 = 0; e2 < 8; e2++) c[e2] += al * (float)s8[e2];
    }
    v8bf outv;
    #pragma unroll
    for (int e2 = 0; e2 < 8; e2++) outv[e2] = (bf16)(c[e2] + (float)hro[e2]);
    *(v8bf*)&crow[l * 8] = outv;
}

// ---------------------------------------------------------------------------
extern "C" void kernel_launch(void* const* d_in, const int* in_sizes, int n_in,
                              void* d_out, int out_size, void* d_ws, size_t ws_size,
                              hipStream_t stream)
{
    const float* spatial  = (const float*)d_in[0];
    const float* gfeat    = (const float*)d_in[1];
    const int*   caps     = (const int*)d_in[2];
    const int*   lengths  = (const int*)d_in[3];
    const float* emb      = (const float*)d_in[4];
    const float* W_init_h = (const float*)d_in[5];
    const float* b_init_h = (const float*)d_in[6];
    const float* W_init_m = (const float*)d_in[7];
    const float* b_init_m = (const float*)d_in[8];
    const float* W_ih     = (const float*)d_in[9];
    const float* b_ih     = (const float*)d_in[10];
    const float* W_hh     = (const float*)d_in[11];
    const float* b_hh     = (const float*)d_in[12];
    const float* Wv       = (const float*)d_in[13];
    const float* bv       = (const float*)d_in[14];
    const float* Wg       = (const float*)d_in[15];
    const float* bg       = (const float*)d_in[16];
    const float* wh       = (const float*)d_in[17];
    const float* bh_att   = (const float*)d_in[18];
    const float* Wp       = (const float*)d_in[19];
    const float* bp       = (const float*)d_in[20];
    float* out = (float*)d_out;
    (void)bh_att;

    char* ws = (char*)d_ws;
    size_t off = 0;
    auto alloc = [&](size_t bytes) -> void* {
        off = (off + 255) & ~(size_t)255;
        void* p = ws + off;
        off += bytes;
        return p;
    };

    bf16* Wp_b    = (bf16*)alloc((size_t)VPAD * D_ * 2);
    bf16* Whh_b   = (bf16*)alloc((size_t)NG_ * D_ * 2);
    bf16* Wih_b   = (bf16*)alloc((size_t)NG_ * XK_ * 2);
    bf16* Xin_b   = (bf16*)alloc((size_t)T_ * B_ * XK_ * 2);
    bf16* Sp_b    = (bf16*)alloc((size_t)B_ * KK_ * D_ * 2);
    bf16* Wv_b    = (bf16*)alloc((size_t)NP_ * D_ * 2);
    bf16* Wg_b    = (bf16*)alloc((size_t)NP_ * D_ * 2);
    bf16* Winit2_b= (bf16*)alloc((size_t)2 * D_ * D_ * 2);
    bf16* Gf_b    = (bf16*)alloc((size_t)B_ * D_ * 2);
    float* bias_comb = (float*)alloc(NG_ * 4);
    float* bias_init = (float*)alloc(2 * D_ * 4);
    float* bv_pad    = (float*)alloc(NP_ * 4);
    float* bg_pad    = (float*)alloc(NP_ * 4);
    bf16* Hb16    = (bf16*)alloc((size_t)(T_ + 1) * B_ * D_ * 2);
    float* mbuf   = (float*)alloc((size_t)B_ * D_ * 4);
    float* Xpre   = (float*)alloc((size_t)T_ * B_ * NG_ * 4);
    float* VprojW = (float*)alloc((size_t)B_ * KK_ * NP_ * 4);
    float* g_allW = (float*)alloc((size_t)T_ * B_ * NP_ * 4);
    bf16* ctx     = (bf16*)alloc((size_t)T_ * B_ * D_ * 2);
    int*  flags   = (int*)alloc((size_t)NBLK * 32 * 4);

    // 1. prep / conversions / flag zeroing
    prep_kernel<<<1024, 256, 0, stream>>>(
        spatial, gfeat, caps, emb, W_init_h, b_init_h, W_init_m, b_init_m,
        W_ih, b_ih, W_hh, b_hh, Wv, bv, Wg, bg, Wp,
        Wp_b, Whh_b, Wih_b, Xin_b, Sp_b, Wv_b, Wg_b, Winit2_b, Gf_b,
        bias_comb, bias_init, bv_pad, bg_pad, flags);

    // 2. h0 (bf16 -> Hb16[0]) and m0 (f32 -> mbuf) in one GEMM
    gemm_bt<3><<<dim3(1, 8), 256, 0, stream>>>(Gf_b, Winit2_b, bias_init,
                                               Hb16, mbuf, B_, 2 * D_, D_, 0, 0, nullptr);

    // 3. V_proj = spatial @ Wv^T + bv  -> [B*K, 128] f32
    gemm_bt<0><<<dim3((B_ * KK_) / 128, 1), 256, 0, stream>>>(
        Sp_b, Wv_b, bv_pad, VprojW, nullptr, B_ * KK_, NP_, D_, NP_, 0, nullptr);

    // 4. Xpre = Xin @ W_ih^T + (b_ih + b_hh)  -> [T*B, 2048] f32
    gemm_bt<0><<<dim3((T_ * B_) / 128, NG_ / 128), 256, 0, stream>>>(
        Xin_b, Wih_b, bias_comb, Xpre, nullptr, T_ * B_, NG_, XK_, NG_, 0, nullptr);

    // 5. all 20 LSTM steps: ONE persistent kernel, XCD-local runner group
    lstm_persist<<<LGRID, 256, 0, stream>>>(Hb16, Whh_b, Xpre, mbuf, lengths, flags);

    // 6. g_all = H[1..T] @ Wg^T + bg  -> [T*B, 128] f32
    gemm_bt<0><<<dim3((T_ * B_) / 128, 1), 256, 0, stream>>>(
        Hb16 + (size_t)B_ * D_, Wg_b, bg_pad, g_allW, nullptr, T_ * B_, NP_, D_, NP_, 0, nullptr);

    // 7. attention + ctx = c + h  (bf16, rows b*T+t)
    attn_kernel<<<B_ * 5, 256, 0, stream>>>(Hb16, g_allW, VprojW, wh, Sp_b, ctx);

    // 8. logits = ctx @ Wp^T + bp, masked, -> d_out [B*T, V]
    gemm_bt<2><<<dim3((T_ * B_) / 128, VPAD / 128), 256, 0, stream>>>(
        ctx, Wp_b, bp, out, nullptr, T_ * B_, VPAD, D_, V_, V_, lengths);
}

// Round 4
// 479.485 us; speedup vs baseline: 1.0469x; 1.0469x over previous
//
#include <hip/hip_runtime.h>
#include <hip/hip_bf16.h>
#include <math.h>

typedef __bf16 bf16;
typedef __bf16 v8bf __attribute__((ext_vector_type(8)));
typedef __bf16 v4bfv __attribute__((ext_vector_type(4)));
typedef float  v4f  __attribute__((ext_vector_type(4)));

#define B_   128
#define KK_  49
#define D_   512
#define E_   256
#define V_   10000
#define T_   20
#define NG_  2048   // 4*D
#define XK_  768    // E+D
#define VPAD 10112  // 79*128 (Wp rows padded)
#define NP_  128    // padded small-N
#define NBLK 64     // flags alloc sizing (2048 ints)
#define LGRID 256   // lstm_persist grid (1 block/CU, co-resident)

// flag-array layout (ints, all zeroed by prep each launch):
//   [0 .. 1023]   step flags: slot s at s*32 (32 slots, line-separated)
//   [1024..1039]  per-XCD registration counters
//   [1040..1055]  per-XCD ready state (0=wait, 1=run, 2=skip)
//   [1056]        leader (0=none, else xcd+1)
//   [1057]        done
#define FLG_CNT    1024
#define FLG_READY  1040
#define FLG_LEADER 1056
#define FLG_DONE   1057

#define GLOAD_LDS16(gp, lp) \
    __builtin_amdgcn_global_load_lds((const __attribute__((address_space(1))) void*)(gp), \
                                     (__attribute__((address_space(3))) void*)(lp), 16, 0, 0)

__device__ inline v4bfv cvt4(float4 v) {
    v4bfv o; o[0] = (bf16)v.x; o[1] = (bf16)v.y; o[2] = (bf16)v.z; o[3] = (bf16)v.w;
    return o;
}

// fast sigmoid/tanh via standard HIP fast-math intrinsics (__expf -> v_exp_f32,
// __fdividef -> fast divide). ~12 instr vs ~35 for libm; saturation exact.
__device__ inline float fsig(float x) {
    return __fdividef(1.f, 1.f + __expf(-x));
}
__device__ inline float ftanh(float x) {
    return 1.f - 2.f * __fdividef(1.f, 1.f + __expf(2.f * x));
}

// ---------------------------------------------------------------------------
// Prep: fp32->bf16 conversions, padding, gather of LSTM input rows, packed
// init weights/biases, barrier-flag zeroing.
// ---------------------------------------------------------------------------
__global__ void prep_kernel(
    const float* __restrict__ spatial, const float* __restrict__ gfeat,
    const int* __restrict__ caps, const float* __restrict__ emb,
    const float* __restrict__ W_init_h, const float* __restrict__ b_init_h,
    const float* __restrict__ W_init_m, const float* __restrict__ b_init_m,
    const float* __restrict__ W_ih, const float* __restrict__ b_ih,
    const float* __restrict__ W_hh, const float* __restrict__ b_hh,
    const float* __restrict__ Wv, const float* __restrict__ bv,
    const float* __restrict__ Wg, const float* __restrict__ bg,
    const float* __restrict__ Wp,
    bf16* __restrict__ Wp_b, bf16* __restrict__ Whh_b, bf16* __restrict__ Wih_b,
    bf16* __restrict__ Xin_b, bf16* __restrict__ Sp_b,
    bf16* __restrict__ Wv_b, bf16* __restrict__ Wg_b,
    bf16* __restrict__ Winit2_b, bf16* __restrict__ Gf_b,
    float* __restrict__ bias_comb, float* __restrict__ bias_init,
    float* __restrict__ bv_pad, float* __restrict__ bg_pad,
    int* __restrict__ flags)
{
    const int stride = gridDim.x * blockDim.x;
    const int tid0 = blockIdx.x * blockDim.x + threadIdx.x;
    const float4 z4 = make_float4(0.f, 0.f, 0.f, 0.f);

    for (int i = tid0; i < NBLK * 32; i += stride) flags[i] = 0;   // covers all flag fields

    for (int i4 = tid0; i4 < VPAD * D_ / 4; i4 += stride) {
        int row = i4 >> 7;
        float4 v = (row < V_) ? ((const float4*)Wp)[i4] : z4;
        ((v4bfv*)Wp_b)[i4] = cvt4(v);
    }
    for (int i4 = tid0; i4 < NG_ * D_ / 4; i4 += stride)
        ((v4bfv*)Whh_b)[i4] = cvt4(((const float4*)W_hh)[i4]);
    for (int i4 = tid0; i4 < NG_ * XK_ / 4; i4 += stride)
        ((v4bfv*)Wih_b)[i4] = cvt4(((const float4*)W_ih)[i4]);
    // Xin rows r = t*128+b : [emb[captions[b,t]], global_feats[b]]
    for (int i4 = tid0; i4 < T_ * B_ * XK_ / 4; i4 += stride) {
        int r = i4 / (XK_ / 4), c4 = i4 - r * (XK_ / 4);
        int c = c4 * 4;
        int t = r >> 7, b = r & 127;
        float4 v;
        if (c < E_) v = *(const float4*)&emb[(long)caps[b * T_ + t] * E_ + c];
        else        v = *(const float4*)&gfeat[(long)b * D_ + (c - E_)];
        ((v4bfv*)Xin_b)[i4] = cvt4(v);
    }
    for (int i4 = tid0; i4 < B_ * KK_ * D_ / 4; i4 += stride)
        ((v4bfv*)Sp_b)[i4] = cvt4(((const float4*)spatial)[i4]);
    for (int i4 = tid0; i4 < NP_ * D_ / 4; i4 += stride) {
        int row = i4 >> 7;
        ((v4bfv*)Wv_b)[i4] = cvt4((row < KK_) ? ((const float4*)Wv)[i4] : z4);
        ((v4bfv*)Wg_b)[i4] = cvt4((row < KK_) ? ((const float4*)Wg)[i4] : z4);
    }
    // packed [W_init_h; W_init_m]  (1024 x 512)
    for (int i4 = tid0; i4 < 2 * D_ * D_ / 4; i4 += stride) {
        int row = i4 >> 7;
        float4 v = (row < D_) ? ((const float4*)W_init_h)[i4]
                              : ((const float4*)W_init_m)[i4 - D_ * (D_ / 4)];
        ((v4bfv*)Winit2_b)[i4] = cvt4(v);
    }
    for (int i4 = tid0; i4 < B_ * D_ / 4; i4 += stride)
        ((v4bfv*)Gf_b)[i4] = cvt4(((const float4*)gfeat)[i4]);
    for (int i = tid0; i < NG_; i += stride) bias_comb[i] = b_ih[i] + b_hh[i];
    for (int i = tid0; i < 2 * D_; i += stride)
        bias_init[i] = (i < D_) ? b_init_h[i] : b_init_m[i - D_];
    for (int i = tid0; i < NP_; i += stride) {
        bv_pad[i] = (i < KK_) ? bv[i] : 0.f;
        bg_pad[i] = (i < KK_) ? bg[i] : 0.f;
    }
}

// ---------------------------------------------------------------------------
// Generic bf16 MFMA GEMM, BK=64: C[M,N] = A[M,K] @ Bm[N,K]^T + bias[n]
// 128x128 tile, 4 waves, each 64x64. blockIdx.x = m-tile (fastest).
// __launch_bounds__(256,4): request 4 blocks/CU (VGPR<=128; now 72).
// OUTMODE: 0=f32, 2=logits (masked f32, n<n_real, stride out_stride),
//          3=split: n<D_ -> bf16 Cout[m*D_+n], else f32 Cout2[m*D_+n-D_]
// ---------------------------------------------------------------------------
template <int OUTMODE>
__global__ __launch_bounds__(256, 4) void gemm_bt(
    const bf16* __restrict__ A, const bf16* __restrict__ Bm,
    const float* __restrict__ bias, void* __restrict__ Cout, void* __restrict__ Cout2,
    int M, int N, int K, int out_stride, int n_real, const int* __restrict__ lengths)
{
    __shared__ bf16 As[2 * 128 * 32];
    __shared__ bf16 Bs[2 * 128 * 32];
    const int m0 = blockIdx.x * 128, n0 = blockIdx.y * 128;
    const int tid = threadIdx.x;
    const int w = tid >> 6, l = tid & 63;
    const int wm = (w >> 1) * 64, wn = (w & 1) * 64;
    const int lr = l & 15, lq = l >> 4;

    v4f acc[4][4] = {};

    for (int k0 = 0; k0 < K; k0 += 64) {
        __syncthreads();
        #pragma unroll
        for (int c = 0; c < 4; c++) {
            int u = c * 256 + tid;
            int h = u >> 9, v = u & 511;
            int row = v >> 2, kc = (v & 3) * 8;
            int u0 = c * 256 + (tid & ~63);
            GLOAD_LDS16(&A[(long)(m0 + row) * K + k0 + h * 32 + kc], &As[u0 * 8]);
            GLOAD_LDS16(&Bm[(long)(n0 + row) * K + k0 + h * 32 + kc], &Bs[u0 * 8]);
        }
        __syncthreads();
        #pragma unroll
        for (int h = 0; h < 2; h++) {
            v8bf af[4], bfv[4];
            #pragma unroll
            for (int s = 0; s < 4; s++) {
                af[s]  = *(const v8bf*)&As[h * 4096 + (wm + s * 16 + lr) * 32 + lq * 8];
                bfv[s] = *(const v8bf*)&Bs[h * 4096 + (wn + s * 16 + lr) * 32 + lq * 8];
            }
            #pragma unroll
            for (int i = 0; i < 4; i++)
                #pragma unroll
                for (int j = 0; j < 4; j++)
                    acc[i][j] = __builtin_amdgcn_mfma_f32_16x16x32_bf16(af[i], bfv[j], acc[i][j], 0, 0, 0);
        }
    }

    #pragma unroll
    for (int i = 0; i < 4; i++)
        #pragma unroll
        for (int j = 0; j < 4; j++)
            #pragma unroll
            for (int r = 0; r < 4; r++) {
                int m = m0 + wm + i * 16 + lq * 4 + r;
                int n = n0 + wn + j * 16 + lr;
                float v = acc[i][j][r];
                if (OUTMODE == 2) {
                    if (n < n_real) {
                        int t = m % T_, b = m / T_;
                        float o = (t < lengths[b]) ? (v + bias[n]) : 0.f;
                        ((float*)Cout)[(long)m * out_stride + n] = o;
                    }
                } else if (OUTMODE == 3) {
                    if (n < D_) ((bf16*)Cout)[(long)m * D_ + n] = (bf16)(v + bias[n]);
                    else ((float*)Cout2)[(long)m * D_ + n - D_] = v + bias[n];
                } else {
                    ((float*)Cout)[(long)m * out_stride + n] = v + bias[n];
                }
            }
}

// ---------------------------------------------------------------------------
// Persistent LSTM recurrence, XCD-LOCAL data exchange.
//
// 256 blocks launched; election (agent-scope atomics, once) picks the first
// XCD to register 32 blocks as the single runner group; everyone else exits
// (losers via ready=2, starved groups via done flag -> no hang under any
// block->XCD mapping).
//
// Runner group: 32 co-XCD blocks = 2 row-halves (rh) x 16 d-slices of 32
// cols. W_hh slice (128 rows x 512) in LDS for all T steps.
// Per-step exchange:
//  - h stores: PLAIN stores (write-through L1 -> land in the shared XCD L2
//    and stay there; round 1's nontemporal stores pushed them to HBM,
//    doubling WRITE_SIZE and putting HBM latency on the critical path).
//  - release: the vmcnt(0) drain __syncthreads performs (h stores ack'd in
//    L2 before any wave passes); then a relaxed agent-scope flag store.
//  - acquire: relaxed agent-scope flag poll; data reads are same-XCD L2 hits
//    (consumer L1 lines are cold: >=1MB same-CU traffic between reuses).
// Each row-half polls only its 16 producer flags.
// ---------------------------------------------------------------------------
__global__ __launch_bounds__(256) void lstm_persist(
    bf16* __restrict__ Hb16, const bf16* __restrict__ Whh_b,
    const float* __restrict__ Xpre, const float* __restrict__ mbuf,
    const int* __restrict__ lengths, int* __restrict__ flags)
{
    __shared__ bf16 Bl[128][520];   // 133,120 B -> 1 block/CU
    __shared__ int s_info[2];
    const int tid = threadIdx.x;

    if (tid == 0) {
        int xcd;
        asm volatile("s_getreg_b32 %0, hwreg(HW_REG_XCC_ID)" : "=s"(xcd));
        xcd &= 15;
        int slot = __hip_atomic_fetch_add(&flags[FLG_CNT + xcd], 1,
                                          __ATOMIC_RELAXED, __HIP_MEMORY_SCOPE_AGENT);
        if (slot == 31) {   // 32nd member: try to claim the runner role for this XCD
            int exp = 0;
            bool win = __hip_atomic_compare_exchange_strong(
                &flags[FLG_LEADER], &exp, xcd + 1,
                __ATOMIC_RELAXED, __ATOMIC_RELAXED, __HIP_MEMORY_SCOPE_AGENT);
            __hip_atomic_store(&flags[FLG_READY + xcd], win ? 1 : 2,
                               __ATOMIC_RELAXED, __HIP_MEMORY_SCOPE_AGENT);
        }
        int st;
        if (slot < 32) {
            int dn;
            do {
                st = __hip_atomic_load(&flags[FLG_READY + xcd],
                                       __ATOMIC_RELAXED, __HIP_MEMORY_SCOPE_AGENT);
                dn = __hip_atomic_load(&flags[FLG_DONE],
                                       __ATOMIC_RELAXED, __HIP_MEMORY_SCOPE_AGENT);
            } while (st == 0 && dn == 0);
            if (st == 0) st = 2;          // starved group released by runner's done
        } else st = 2;                    // surplus block on a full XCD
        s_info[0] = st;
        s_info[1] = slot;
    }
    __syncthreads();
    if (s_info[0] != 1) return;

    const int slot = s_info[1];
    const int w = tid >> 6, l = tid & 63;
    const int lr = l & 15, lq = l >> 4;
    const int rh = slot & 1;              // row-half: batch rows [rh*64, rh*64+64)
    const int d0v = (slot >> 1) * 32;     // 32 d-cols
    const int b0 = rh * 64;

    // stage W_hh slice: Bl[j] <- Whh row (j>>5)*512 + d0v + (j&31), j in [0,128)
    for (int u = tid; u < 128 * 64; u += 256) {
        int row = u >> 6, kc = (u & 63) * 8;
        int g = row >> 5, dd = row & 31;
        *(v8bf*)&Bl[row][kc] = *(const v8bf*)&Whh_b[(long)(g * D_ + d0v + dd) * D_ + kc];
    }

    // per-thread state: r=0..3 -> b = b0 + w*16 + lq*4 + r ; dh=0..1 -> d = d0v + dh*16 + lr
    const int brow = b0 + w * 16 + lq * 4;
    float m_st[4][2], h_st[4][2], xpf[4][2][4];
    int lenr[4];
    #pragma unroll
    for (int r = 0; r < 4; r++) {
        int b = brow + r;
        lenr[r] = lengths[b];
        #pragma unroll
        for (int dh = 0; dh < 2; dh++) {
            int d = d0v + dh * 16 + lr;
            m_st[r][dh] = mbuf[(long)b * D_ + d];
            h_st[r][dh] = (float)Hb16[(long)b * D_ + d];
            #pragma unroll
            for (int g = 0; g < 4; g++)
                xpf[r][dh][g] = Xpre[(long)b * NG_ + g * D_ + d];
        }
    }
    __syncthreads();

    for (int t = 0; t < T_; t++) {
        // gates = H[t] @ Whh_slice^T : wave w owns m-rows b0+w*16..+15
        // acc[nt] <-> gate g = nt>>1, d = d0v + (nt&1)*16 + lr
        const bf16* Arow = Hb16 + (long)t * B_ * D_ + (long)(b0 + w * 16 + lr) * D_;
        v4f acc[8] = {};
        #pragma unroll
        for (int kk = 0; kk < 16; kk++) {
            v8bf a = *(const v8bf*)&Arow[kk * 32 + lq * 8];
            #pragma unroll
            for (int nt = 0; nt < 8; nt++) {
                v8bf bv = *(const v8bf*)&Bl[nt * 16 + lr][kk * 32 + lq * 8];
                acc[nt] = __builtin_amdgcn_mfma_f32_16x16x32_bf16(a, bv, acc[nt], 0, 0, 0);
            }
        }

        bf16* hn = Hb16 + (long)(t + 1) * B_ * D_;
        #pragma unroll
        for (int r = 0; r < 4; r++) {
            int b = brow + r;
            bool active = t < lenr[r];
            #pragma unroll
            for (int dh = 0; dh < 2; dh++) {
                float gi = fsig (acc[0 + dh][r] + xpf[r][dh][0]);
                float gf = fsig (acc[2 + dh][r] + xpf[r][dh][1]);
                float gc = ftanh(acc[4 + dh][r] + xpf[r][dh][2]);
                float go = fsig (acc[6 + dh][r] + xpf[r][dh][3]);
                float m_new = gf * m_st[r][dh] + gi * gc;
                float h_new = go * ftanh(m_new);
                m_st[r][dh] = active ? m_new : m_st[r][dh];
                h_st[r][dh] = active ? h_new : h_st[r][dh];
                // PLAIN store: write-through to the shared XCD L2 and stays there
                hn[(long)b * D_ + d0v + dh * 16 + lr] = (bf16)h_st[r][dh];
            }
        }

        if (t + 1 < T_) {
            __syncthreads();   // per-wave vmcnt(0) drain -> h-stores ack'd in shared L2
            if (tid == 0)
                __hip_atomic_store(&flags[slot * 32], t + 1,
                                   __ATOMIC_RELAXED, __HIP_MEMORY_SCOPE_AGENT);
            // prefetch next step's Xpre while peers arrive
            #pragma unroll
            for (int r = 0; r < 4; r++) {
                int b = brow + r;
                #pragma unroll
                for (int dh = 0; dh < 2; dh++)
                    #pragma unroll
                    for (int g = 0; g < 4; g++)
                        xpf[r][dh][g] = Xpre[(long)(t + 1) * B_ * NG_ + (long)b * NG_
                                             + g * D_ + d0v + dh * 16 + lr];
            }
            if (w == 0) {      // lane i (<16) polls producer slot 2*i+rh (same row-half)
                int need = t + 1, v = need;
                do {
                    if (l < 16)
                        v = __hip_atomic_load(&flags[(2 * l + rh) * 32],
                                              __ATOMIC_RELAXED, __HIP_MEMORY_SCOPE_AGENT);
                } while (__any(v < need));
            }
            __syncthreads();
        }
    }

    if (slot == 0 && tid == 0)   // release any starved incomplete groups
        __hip_atomic_store(&flags[FLG_DONE], 1, __ATOMIC_RELAXED, __HIP_MEMORY_SCOPE_AGENT);
}

// ---------------------------------------------------------------------------
// Attention + context. 4 waves/block share b (Vproj tile staged in LDS once);
// wave owns one t. ctx[b*T+t] = softmax_k(wh.tanh(Vproj+Wg h))@spatial[b]+h_t.
// ---------------------------------------------------------------------------
__global__ __launch_bounds__(256) void attn_kernel(
    const bf16* __restrict__ Hb16, const float* __restrict__ g_all,
    const float* __restrict__ Vproj, const float* __restrict__ wh,
    const bf16* __restrict__ Sp_b, bf16* __restrict__ ctx)
{
    const int w = threadIdx.x >> 6, l = threadIdx.x & 63;
    const int b = blockIdx.x / 5, tg = blockIdx.x % 5;
    const int t = tg * 4 + w;
    const int r = t * 128 + b;
    __shared__ float svp[KK_][53];
    __shared__ float sg[4][64], sal[4][64], swh[64];

    for (int p = threadIdx.x; p < KK_ * 64; p += 256) {
        int k = p >> 6, j = p & 63;
        if (j < KK_) svp[k][j] = Vproj[((long)b * KK_ + k) * NP_ + j];
    }
    if (w == 0) swh[l] = (l < KK_) ? wh[l] : 0.f;
    sg[w][l] = (l < KK_) ? g_all[(long)r * NP_ + l] : 0.f;
    __syncthreads();

    float z = -1e30f;
    if (l < KK_) {
        float a = 0.f;
        for (int j = 0; j < KK_; j++)
            a += swh[j] * ftanh(svp[l][j] + sg[w][j]);
        z = a;
    }
    float mx = z;
    #pragma unroll
    for (int o = 32; o > 0; o >>= 1) mx = fmaxf(mx, __shfl_xor(mx, o));
    float e = (l < KK_) ? __expf(z - mx) : 0.f;
    float sm = e;
    #pragma unroll
    for (int o = 32; o > 0; o >>= 1) sm += __shfl_xor(sm, o);
    sal[w][l] = e / sm;
    __syncthreads();

    const bf16* hrow = Hb16 + (long)(t + 1) * B_ * D_ + (long)b * D_;
    const bf16* sp = Sp_b + (long)b * KK_ * D_;
    bf16* crow = ctx + (long)(b * T_ + t) * D_;
    v8bf hro = *(const v8bf*)&hrow[l * 8];
    float c[8] = {};
    for (int k = 0; k < KK_; k++) {
        v8bf s8 = *(const v8bf*)&sp[k * D_ + l * 8];
        float al = sal[w][k];
        #pragma unroll
        for (int e2 = 0; e2 < 8; e2++) c[e2] += al * (float)s8[e2];
    }
    v8bf outv;
    #pragma unroll
    for (int e2 = 0; e2 < 8; e2++) outv[e2] = (bf16)(c[e2] + (float)hro[e2]);
    *(v8bf*)&crow[l * 8] = outv;
}

// ---------------------------------------------------------------------------
extern "C" void kernel_launch(void* const* d_in, const int* in_sizes, int n_in,
                              void* d_out, int out_size, void* d_ws, size_t ws_size,
                              hipStream_t stream)
{
    const float* spatial  = (const float*)d_in[0];
    const float* gfeat    = (const float*)d_in[1];
    const int*   caps     = (const int*)d_in[2];
    const int*   lengths  = (const int*)d_in[3];
    const float* emb      = (const float*)d_in[4];
    const float* W_init_h = (const float*)d_in[5];
    const float* b_init_h = (const float*)d_in[6];
    const float* W_init_m = (const float*)d_in[7];
    const float* b_init_m = (const float*)d_in[8];
    const float* W_ih     = (const float*)d_in[9];
    const float* b_ih     = (const float*)d_in[10];
    const float* W_hh     = (const float*)d_in[11];
    const float* b_hh     = (const float*)d_in[12];
    const float* Wv       = (const float*)d_in[13];
    const float* bv       = (const float*)d_in[14];
    const float* Wg       = (const float*)d_in[15];
    const float* bg       = (const float*)d_in[16];
    const float* wh       = (const float*)d_in[17];
    const float* bh_att   = (const float*)d_in[18];
    const float* Wp       = (const float*)d_in[19];
    const float* bp       = (const float*)d_in[20];
    float* out = (float*)d_out;
    (void)bh_att;

    char* ws = (char*)d_ws;
    size_t off = 0;
    auto alloc = [&](size_t bytes) -> void* {
        off = (off + 255) & ~(size_t)255;
        void* p = ws + off;
        off += bytes;
        return p;
    };

    bf16* Wp_b    = (bf16*)alloc((size_t)VPAD * D_ * 2);
    bf16* Whh_b   = (bf16*)alloc((size_t)NG_ * D_ * 2);
    bf16* Wih_b   = (bf16*)alloc((size_t)NG_ * XK_ * 2);
    bf16* Xin_b   = (bf16*)alloc((size_t)T_ * B_ * XK_ * 2);
    bf16* Sp_b    = (bf16*)alloc((size_t)B_ * KK_ * D_ * 2);
    bf16* Wv_b    = (bf16*)alloc((size_t)NP_ * D_ * 2);
    bf16* Wg_b    = (bf16*)alloc((size_t)NP_ * D_ * 2);
    bf16* Winit2_b= (bf16*)alloc((size_t)2 * D_ * D_ * 2);
    bf16* Gf_b    = (bf16*)alloc((size_t)B_ * D_ * 2);
    float* bias_comb = (float*)alloc(NG_ * 4);
    float* bias_init = (float*)alloc(2 * D_ * 4);
    float* bv_pad    = (float*)alloc(NP_ * 4);
    float* bg_pad    = (float*)alloc(NP_ * 4);
    bf16* Hb16    = (bf16*)alloc((size_t)(T_ + 1) * B_ * D_ * 2);
    float* mbuf   = (float*)alloc((size_t)B_ * D_ * 4);
    float* Xpre   = (float*)alloc((size_t)T_ * B_ * NG_ * 4);
    float* VprojW = (float*)alloc((size_t)B_ * KK_ * NP_ * 4);
    float* g_allW = (float*)alloc((size_t)T_ * B_ * NP_ * 4);
    bf16* ctx     = (bf16*)alloc((size_t)T_ * B_ * D_ * 2);
    int*  flags   = (int*)alloc((size_t)NBLK * 32 * 4);

    // 1. prep / conversions / flag zeroing
    prep_kernel<<<1024, 256, 0, stream>>>(
        spatial, gfeat, caps, emb, W_init_h, b_init_h, W_init_m, b_init_m,
        W_ih, b_ih, W_hh, b_hh, Wv, bv, Wg, bg, Wp,
        Wp_b, Whh_b, Wih_b, Xin_b, Sp_b, Wv_b, Wg_b, Winit2_b, Gf_b,
        bias_comb, bias_init, bv_pad, bg_pad, flags);

    // 2. h0 (bf16 -> Hb16[0]) and m0 (f32 -> mbuf) in one GEMM
    gemm_bt<3><<<dim3(1, 8), 256, 0, stream>>>(Gf_b, Winit2_b, bias_init,
                                               Hb16, mbuf, B_, 2 * D_, D_, 0, 0, nullptr);

    // 3. V_proj = spatial @ Wv^T + bv  -> [B*K, 128] f32
    gemm_bt<0><<<dim3((B_ * KK_) / 128, 1), 256, 0, stream>>>(
        Sp_b, Wv_b, bv_pad, VprojW, nullptr, B_ * KK_, NP_, D_, NP_, 0, nullptr);

    // 4. Xpre = Xin @ W_ih^T + (b_ih + b_hh)  -> [T*B, 2048] f32
    gemm_bt<0><<<dim3((T_ * B_) / 128, NG_ / 128), 256, 0, stream>>>(
        Xin_b, Wih_b, bias_comb, Xpre, nullptr, T_ * B_, NG_, XK_, NG_, 0, nullptr);

    // 5. all 20 LSTM steps: ONE persistent kernel, XCD-local runner group
    lstm_persist<<<LGRID, 256, 0, stream>>>(Hb16, Whh_b, Xpre, mbuf, lengths, flags);

    // 6. g_all = H[1..T] @ Wg^T + bg  -> [T*B, 128] f32
    gemm_bt<0><<<dim3((T_ * B_) / 128, 1), 256, 0, stream>>>(
        Hb16 + (size_t)B_ * D_, Wg_b, bg_pad, g_allW, nullptr, T_ * B_, NP_, D_, NP_, 0, nullptr);

    // 7. attention + ctx = c + h  (bf16, rows b*T+t)
    attn_kernel<<<B_ * 5, 256, 0, stream>>>(Hb16, g_allW, VprojW, wh, Sp_b, ctx);

    // 8. logits = ctx @ Wp^T + bp, masked, -> d_out [B*T, V]
    gemm_bt<2><<<dim3((T_ * B_) / 128, VPAD / 128), 256, 0, stream>>>(
        ctx, Wp_b, bp, out, nullptr, T_ * B_, VPAD, D_, V_, V_, lengths);
}

// Round 5
// 477.734 us; speedup vs baseline: 1.0507x; 1.0037x over previous
//
#include <hip/hip_runtime.h>
#include <hip/hip_bf16.h>
#include <math.h>

typedef __bf16 bf16;
typedef __bf16 v8bf __attribute__((ext_vector_type(8)));
typedef __bf16 v4bfv __attribute__((ext_vector_type(4)));
typedef float  v4f  __attribute__((ext_vector_type(4)));

#define B_   128
#define KK_  49
#define D_   512
#define E_   256
#define V_   10000
#define T_   20
#define NG_  2048   // 4*D
#define XK_  768    // E+D
#define VPAD 10112  // 79*128 (Wp rows padded)
#define NP_  128    // padded small-N
#define NBLK 64     // flags alloc sizing (2048 ints)
#define LGRID 256   // lstm_persist grid (1 block/CU, co-resident)

// flag-array layout (ints, all zeroed by prep each launch):
//   [0]           progress counter, row-half 0 (target 16*(t+1))
//   [64]          progress counter, row-half 1 (separate 256B line)
//   [1024..1039]  per-XCD registration counters
//   [1040..1055]  per-XCD ready state (0=wait, 1=run, 2=skip)
//   [1056]        leader (0=none, else xcd+1)
//   [1057]        done
#define FLG_CNT    1024
#define FLG_READY  1040
#define FLG_LEADER 1056
#define FLG_DONE   1057

#define GLOAD_LDS16(gp, lp) \
    __builtin_amdgcn_global_load_lds((const __attribute__((address_space(1))) void*)(gp), \
                                     (__attribute__((address_space(3))) void*)(lp), 16, 0, 0)

__device__ inline v4bfv cvt4(float4 v) {
    v4bfv o; o[0] = (bf16)v.x; o[1] = (bf16)v.y; o[2] = (bf16)v.z; o[3] = (bf16)v.w;
    return o;
}

// fast sigmoid/tanh via standard HIP fast-math intrinsics (__expf -> v_exp_f32,
// __fdividef -> fast divide). ~12 instr vs ~35 for libm; saturation exact.
__device__ inline float fsig(float x) {
    return __fdividef(1.f, 1.f + __expf(-x));
}
__device__ inline float ftanh(float x) {
    return 1.f - 2.f * __fdividef(1.f, 1.f + __expf(2.f * x));
}

// ---------------------------------------------------------------------------
// Prep: fp32->bf16 conversions, padding, gather of LSTM input rows, packed
// init weights/biases, barrier-flag zeroing.
// ---------------------------------------------------------------------------
__global__ void prep_kernel(
    const float* __restrict__ spatial, const float* __restrict__ gfeat,
    const int* __restrict__ caps, const float* __restrict__ emb,
    const float* __restrict__ W_init_h, const float* __restrict__ b_init_h,
    const float* __restrict__ W_init_m, const float* __restrict__ b_init_m,
    const float* __restrict__ W_ih, const float* __restrict__ b_ih,
    const float* __restrict__ W_hh, const float* __restrict__ b_hh,
    const float* __restrict__ Wv, const float* __restrict__ bv,
    const float* __restrict__ Wg, const float* __restrict__ bg,
    const float* __restrict__ Wp,
    bf16* __restrict__ Wp_b, bf16* __restrict__ Whh_b, bf16* __restrict__ Wih_b,
    bf16* __restrict__ Xin_b, bf16* __restrict__ Sp_b,
    bf16* __restrict__ Wv_b, bf16* __restrict__ Wg_b,
    bf16* __restrict__ Winit2_b, bf16* __restrict__ Gf_b,
    float* __restrict__ bias_comb, float* __restrict__ bias_init,
    float* __restrict__ bv_pad, float* __restrict__ bg_pad,
    int* __restrict__ flags)
{
    const int stride = gridDim.x * blockDim.x;
    const int tid0 = blockIdx.x * blockDim.x + threadIdx.x;
    const float4 z4 = make_float4(0.f, 0.f, 0.f, 0.f);

    for (int i = tid0; i < NBLK * 32; i += stride) flags[i] = 0;   // covers all flag fields

    for (int i4 = tid0; i4 < VPAD * D_ / 4; i4 += stride) {
        int row = i4 >> 7;
        float4 v = (row < V_) ? ((const float4*)Wp)[i4] : z4;
        ((v4bfv*)Wp_b)[i4] = cvt4(v);
    }
    for (int i4 = tid0; i4 < NG_ * D_ / 4; i4 += stride)
        ((v4bfv*)Whh_b)[i4] = cvt4(((const float4*)W_hh)[i4]);
    for (int i4 = tid0; i4 < NG_ * XK_ / 4; i4 += stride)
        ((v4bfv*)Wih_b)[i4] = cvt4(((const float4*)W_ih)[i4]);
    // Xin rows r = t*128+b : [emb[captions[b,t]], global_feats[b]]
    for (int i4 = tid0; i4 < T_ * B_ * XK_ / 4; i4 += stride) {
        int r = i4 / (XK_ / 4), c4 = i4 - r * (XK_ / 4);
        int c = c4 * 4;
        int t = r >> 7, b = r & 127;
        float4 v;
        if (c < E_) v = *(const float4*)&emb[(long)caps[b * T_ + t] * E_ + c];
        else        v = *(const float4*)&gfeat[(long)b * D_ + (c - E_)];
        ((v4bfv*)Xin_b)[i4] = cvt4(v);
    }
    for (int i4 = tid0; i4 < B_ * KK_ * D_ / 4; i4 += stride)
        ((v4bfv*)Sp_b)[i4] = cvt4(((const float4*)spatial)[i4]);
    for (int i4 = tid0; i4 < NP_ * D_ / 4; i4 += stride) {
        int row = i4 >> 7;
        ((v4bfv*)Wv_b)[i4] = cvt4((row < KK_) ? ((const float4*)Wv)[i4] : z4);
        ((v4bfv*)Wg_b)[i4] = cvt4((row < KK_) ? ((const float4*)Wg)[i4] : z4);
    }
    // packed [W_init_h; W_init_m]  (1024 x 512)
    for (int i4 = tid0; i4 < 2 * D_ * D_ / 4; i4 += stride) {
        int row = i4 >> 7;
        float4 v = (row < D_) ? ((const float4*)W_init_h)[i4]
                              : ((const float4*)W_init_m)[i4 - D_ * (D_ / 4)];
        ((v4bfv*)Winit2_b)[i4] = cvt4(v);
    }
    for (int i4 = tid0; i4 < B_ * D_ / 4; i4 += stride)
        ((v4bfv*)Gf_b)[i4] = cvt4(((const float4*)gfeat)[i4]);
    for (int i = tid0; i < NG_; i += stride) bias_comb[i] = b_ih[i] + b_hh[i];
    for (int i = tid0; i < 2 * D_; i += stride)
        bias_init[i] = (i < D_) ? b_init_h[i] : b_init_m[i - D_];
    for (int i = tid0; i < NP_; i += stride) {
        bv_pad[i] = (i < KK_) ? bv[i] : 0.f;
        bg_pad[i] = (i < KK_) ? bg[i] : 0.f;
    }
}

// ---------------------------------------------------------------------------
// Generic bf16 MFMA GEMM, BK=64: C[M,N] = A[M,K] @ Bm[N,K]^T + bias[n]
// 128x128 tile, 4 waves, each 64x64. blockIdx.x = m-tile (fastest).
// __launch_bounds__(256,4): request 4 blocks/CU (VGPR<=128; now 72).
// OUTMODE: 0=f32, 2=logits (masked f32, n<n_real, stride out_stride),
//          3=split: n<D_ -> bf16 Cout[m*D_+n], else f32 Cout2[m*D_+n-D_]
// ---------------------------------------------------------------------------
template <int OUTMODE>
__global__ __launch_bounds__(256, 4) void gemm_bt(
    const bf16* __restrict__ A, const bf16* __restrict__ Bm,
    const float* __restrict__ bias, void* __restrict__ Cout, void* __restrict__ Cout2,
    int M, int N, int K, int out_stride, int n_real, const int* __restrict__ lengths)
{
    __shared__ bf16 As[2 * 128 * 32];
    __shared__ bf16 Bs[2 * 128 * 32];
    const int m0 = blockIdx.x * 128, n0 = blockIdx.y * 128;
    const int tid = threadIdx.x;
    const int w = tid >> 6, l = tid & 63;
    const int wm = (w >> 1) * 64, wn = (w & 1) * 64;
    const int lr = l & 15, lq = l >> 4;

    v4f acc[4][4] = {};

    for (int k0 = 0; k0 < K; k0 += 64) {
        __syncthreads();
        #pragma unroll
        for (int c = 0; c < 4; c++) {
            int u = c * 256 + tid;
            int h = u >> 9, v = u & 511;
            int row = v >> 2, kc = (v & 3) * 8;
            int u0 = c * 256 + (tid & ~63);
            GLOAD_LDS16(&A[(long)(m0 + row) * K + k0 + h * 32 + kc], &As[u0 * 8]);
            GLOAD_LDS16(&Bm[(long)(n0 + row) * K + k0 + h * 32 + kc], &Bs[u0 * 8]);
        }
        __syncthreads();
        #pragma unroll
        for (int h = 0; h < 2; h++) {
            v8bf af[4], bfv[4];
            #pragma unroll
            for (int s = 0; s < 4; s++) {
                af[s]  = *(const v8bf*)&As[h * 4096 + (wm + s * 16 + lr) * 32 + lq * 8];
                bfv[s] = *(const v8bf*)&Bs[h * 4096 + (wn + s * 16 + lr) * 32 + lq * 8];
            }
            #pragma unroll
            for (int i = 0; i < 4; i++)
                #pragma unroll
                for (int j = 0; j < 4; j++)
                    acc[i][j] = __builtin_amdgcn_mfma_f32_16x16x32_bf16(af[i], bfv[j], acc[i][j], 0, 0, 0);
        }
    }

    #pragma unroll
    for (int i = 0; i < 4; i++)
        #pragma unroll
        for (int j = 0; j < 4; j++)
            #pragma unroll
            for (int r = 0; r < 4; r++) {
                int m = m0 + wm + i * 16 + lq * 4 + r;
                int n = n0 + wn + j * 16 + lr;
                float v = acc[i][j][r];
                if (OUTMODE == 2) {
                    if (n < n_real) {
                        int t = m % T_, b = m / T_;
                        float o = (t < lengths[b]) ? (v + bias[n]) : 0.f;
                        ((float*)Cout)[(long)m * out_stride + n] = o;
                    }
                } else if (OUTMODE == 3) {
                    if (n < D_) ((bf16*)Cout)[(long)m * D_ + n] = (bf16)(v + bias[n]);
                    else ((float*)Cout2)[(long)m * D_ + n - D_] = v + bias[n];
                } else {
                    ((float*)Cout)[(long)m * out_stride + n] = v + bias[n];
                }
            }
}

// ---------------------------------------------------------------------------
// Persistent LSTM recurrence, XCD-LOCAL data exchange, RMW-counter barrier.
//
// 256 blocks launched; election (agent-scope atomics, once) picks the first
// XCD to register 32 blocks as the single runner group; everyone else exits
// (losers via ready=2, starved groups via done flag -> no hang under any
// block->XCD mapping).
//
// Runner group: 32 co-XCD blocks = 2 row-halves (rh) x 16 d-slices of 32
// cols. W_hh slice (128 rows x 512) in LDS for all T steps.
// Per-step exchange:
//  - h stores: plain stores (write-through -> land in the shared XCD L2).
//  - release: vmcnt(0) drain at __syncthreads, then tid0 does an atomic
//    fetch_add(+1) on its row-half's progress counter.
//  - acquire: tid0 spins on fetch_add(+0) until counter >= 16*(t+1).
//    RMW polls execute AT THE COHERENT POINT — they can never be served
//    from a stale L1 line (suspected cause of the ~8us/step barrier floor
//    seen with plain atomic-load polling in R0/R1/R4).
//  - w0's Xpre prefetch is issued AFTER the poll so the poll's vmcnt wait
//    doesn't first drain 32 HBM prefetch loads; the prefetch still overlaps
//    the next step's MFMA phase (>1us) before its first use.
// ---------------------------------------------------------------------------
__global__ __launch_bounds__(256) void lstm_persist(
    bf16* __restrict__ Hb16, const bf16* __restrict__ Whh_b,
    const float* __restrict__ Xpre, const float* __restrict__ mbuf,
    const int* __restrict__ lengths, int* __restrict__ flags)
{
    __shared__ bf16 Bl[128][520];   // 133,120 B -> 1 block/CU
    __shared__ int s_info[2];
    const int tid = threadIdx.x;

    if (tid == 0) {
        int xcd;
        asm volatile("s_getreg_b32 %0, hwreg(HW_REG_XCC_ID)" : "=s"(xcd));
        xcd &= 15;
        int slot = __hip_atomic_fetch_add(&flags[FLG_CNT + xcd], 1,
                                          __ATOMIC_RELAXED, __HIP_MEMORY_SCOPE_AGENT);
        if (slot == 31) {   // 32nd member: try to claim the runner role for this XCD
            int exp = 0;
            bool win = __hip_atomic_compare_exchange_strong(
                &flags[FLG_LEADER], &exp, xcd + 1,
                __ATOMIC_RELAXED, __ATOMIC_RELAXED, __HIP_MEMORY_SCOPE_AGENT);
            __hip_atomic_store(&flags[FLG_READY + xcd], win ? 1 : 2,
                               __ATOMIC_RELAXED, __HIP_MEMORY_SCOPE_AGENT);
        }
        int st;
        if (slot < 32) {
            int dn;
            do {
                st = __hip_atomic_load(&flags[FLG_READY + xcd],
                                       __ATOMIC_RELAXED, __HIP_MEMORY_SCOPE_AGENT);
                dn = __hip_atomic_load(&flags[FLG_DONE],
                                       __ATOMIC_RELAXED, __HIP_MEMORY_SCOPE_AGENT);
            } while (st == 0 && dn == 0);
            if (st == 0) st = 2;          // starved group released by runner's done
        } else st = 2;                    // surplus block on a full XCD
        s_info[0] = st;
        s_info[1] = slot;
    }
    __syncthreads();
    if (s_info[0] != 1) return;

    const int slot = s_info[1];
    const int w = tid >> 6, l = tid & 63;
    const int lr = l & 15, lq = l >> 4;
    const int rh = slot & 1;              // row-half: batch rows [rh*64, rh*64+64)
    const int d0v = (slot >> 1) * 32;     // 32 d-cols
    const int b0 = rh * 64;
    int* const prog = &flags[rh ? 64 : 0];   // per-half progress counter

    // stage W_hh slice: Bl[j] <- Whh row (j>>5)*512 + d0v + (j&31), j in [0,128)
    for (int u = tid; u < 128 * 64; u += 256) {
        int row = u >> 6, kc = (u & 63) * 8;
        int g = row >> 5, dd = row & 31;
        *(v8bf*)&Bl[row][kc] = *(const v8bf*)&Whh_b[(long)(g * D_ + d0v + dd) * D_ + kc];
    }

    // per-thread state: r=0..3 -> b = b0 + w*16 + lq*4 + r ; dh=0..1 -> d = d0v + dh*16 + lr
    const int brow = b0 + w * 16 + lq * 4;
    float m_st[4][2], h_st[4][2], xpf[4][2][4];
    int lenr[4];
    #pragma unroll
    for (int r = 0; r < 4; r++) {
        int b = brow + r;
        lenr[r] = lengths[b];
        #pragma unroll
        for (int dh = 0; dh < 2; dh++) {
            int d = d0v + dh * 16 + lr;
            m_st[r][dh] = mbuf[(long)b * D_ + d];
            h_st[r][dh] = (float)Hb16[(long)b * D_ + d];
            #pragma unroll
            for (int g = 0; g < 4; g++)
                xpf[r][dh][g] = Xpre[(long)b * NG_ + g * D_ + d];
        }
    }
    __syncthreads();

    for (int t = 0; t < T_; t++) {
        // gates = H[t] @ Whh_slice^T : wave w owns m-rows b0+w*16..+15
        // acc[nt] <-> gate g = nt>>1, d = d0v + (nt&1)*16 + lr
        const bf16* Arow = Hb16 + (long)t * B_ * D_ + (long)(b0 + w * 16 + lr) * D_;
        v4f acc[8] = {};
        #pragma unroll
        for (int kk = 0; kk < 16; kk++) {
            v8bf a = *(const v8bf*)&Arow[kk * 32 + lq * 8];
            #pragma unroll
            for (int nt = 0; nt < 8; nt++) {
                v8bf bv = *(const v8bf*)&Bl[nt * 16 + lr][kk * 32 + lq * 8];
                acc[nt] = __builtin_amdgcn_mfma_f32_16x16x32_bf16(a, bv, acc[nt], 0, 0, 0);
            }
        }

        bf16* hn = Hb16 + (long)(t + 1) * B_ * D_;
        #pragma unroll
        for (int r = 0; r < 4; r++) {
            int b = brow + r;
            bool active = t < lenr[r];
            #pragma unroll
            for (int dh = 0; dh < 2; dh++) {
                float gi = fsig (acc[0 + dh][r] + xpf[r][dh][0]);
                float gf = fsig (acc[2 + dh][r] + xpf[r][dh][1]);
                float gc = ftanh(acc[4 + dh][r] + xpf[r][dh][2]);
                float go = fsig (acc[6 + dh][r] + xpf[r][dh][3]);
                float m_new = gf * m_st[r][dh] + gi * gc;
                float h_new = go * ftanh(m_new);
                m_st[r][dh] = active ? m_new : m_st[r][dh];
                h_st[r][dh] = active ? h_new : h_st[r][dh];
                // plain store: lands in the shared XCD L2 and stays there
                hn[(long)b * D_ + d0v + dh * 16 + lr] = (bf16)h_st[r][dh];
            }
        }

        if (t + 1 < T_) {
            __syncthreads();   // per-wave vmcnt(0) drain -> h-stores ack'd in shared L2
            if (tid == 0) {
                // publish: +1 for this block; then RMW-poll (L1-proof) until all
                // 16 producers of this row-half have published step t+1.
                const int target = 16 * (t + 1);
                int c = __hip_atomic_fetch_add(prog, 1,
                          __ATOMIC_RELAXED, __HIP_MEMORY_SCOPE_AGENT) + 1;
                while (c < target)
                    c = __hip_atomic_fetch_add(prog, 0,
                          __ATOMIC_RELAXED, __HIP_MEMORY_SCOPE_AGENT);
            }
            // prefetch next step's Xpre (w0 reaches here after the poll, so the
            // poll's vmcnt wait never drains these HBM loads; first use is after
            // the next MFMA phase, which covers the latency)
            #pragma unroll
            for (int r = 0; r < 4; r++) {
                int b = brow + r;
                #pragma unroll
                for (int dh = 0; dh < 2; dh++)
                    #pragma unroll
                    for (int g = 0; g < 4; g++)
                        xpf[r][dh][g] = Xpre[(long)(t + 1) * B_ * NG_ + (long)b * NG_
                                             + g * D_ + d0v + dh * 16 + lr];
            }
            __syncthreads();   // all waves gated on tid0's poll completion
        }
    }

    if (slot == 0 && tid == 0)   // release any starved incomplete groups
        __hip_atomic_store(&flags[FLG_DONE], 1, __ATOMIC_RELAXED, __HIP_MEMORY_SCOPE_AGENT);
}

// ---------------------------------------------------------------------------
// Attention + context. 4 waves/block share b (Vproj tile staged in LDS once);
// wave owns one t. ctx[b*T+t] = softmax_k(wh.tanh(Vproj+Wg h))@spatial[b]+h_t.
// ---------------------------------------------------------------------------
__global__ __launch_bounds__(256) void attn_kernel(
    const bf16* __restrict__ Hb16, const float* __restrict__ g_all,
    const float* __restrict__ Vproj, const float* __restrict__ wh,
    const bf16* __restrict__ Sp_b, bf16* __restrict__ ctx)
{
    const int w = threadIdx.x >> 6, l = threadIdx.x & 63;
    const int b = blockIdx.x / 5, tg = blockIdx.x % 5;
    const int t = tg * 4 + w;
    const int r = t * 128 + b;
    __shared__ float svp[KK_][53];
    __shared__ float sg[4][64], sal[4][64], swh[64];

    for (int p = threadIdx.x; p < KK_ * 64; p += 256) {
        int k = p >> 6, j = p & 63;
        if (j < KK_) svp[k][j] = Vproj[((long)b * KK_ + k) * NP_ + j];
    }
    if (w == 0) swh[l] = (l < KK_) ? wh[l] : 0.f;
    sg[w][l] = (l < KK_) ? g_all[(long)r * NP_ + l] : 0.f;
    __syncthreads();

    float z = -1e30f;
    if (l < KK_) {
        float a = 0.f;
        for (int j = 0; j < KK_; j++)
            a += swh[j] * ftanh(svp[l][j] + sg[w][j]);
        z = a;
    }
    float mx = z;
    #pragma unroll
    for (int o = 32; o > 0; o >>= 1) mx = fmaxf(mx, __shfl_xor(mx, o));
    float e = (l < KK_) ? __expf(z - mx) : 0.f;
    float sm = e;
    #pragma unroll
    for (int o = 32; o > 0; o >>= 1) sm += __shfl_xor(sm, o);
    sal[w][l] = e / sm;
    __syncthreads();

    const bf16* hrow = Hb16 + (long)(t + 1) * B_ * D_ + (long)b * D_;
    const bf16* sp = Sp_b + (long)b * KK_ * D_;
    bf16* crow = ctx + (long)(b * T_ + t) * D_;
    v8bf hro = *(const v8bf*)&hrow[l * 8];
    float c[8] = {};
    for (int k = 0; k < KK_; k++) {
        v8bf s8 = *(const v8bf*)&sp[k * D_ + l * 8];
        float al = sal[w][k];
        #pragma unroll
        for (int e2 = 0; e2 < 8; e2++) c[e2] += al * (float)s8[e2];
    }
    v8bf outv;
    #pragma unroll
    for (int e2 = 0; e2 < 8; e2++) outv[e2] = (bf16)(c[e2] + (float)hro[e2]);
    *(v8bf*)&crow[l * 8] = outv;
}

// ---------------------------------------------------------------------------
extern "C" void kernel_launch(void* const* d_in, const int* in_sizes, int n_in,
                              void* d_out, int out_size, void* d_ws, size_t ws_size,
                              hipStream_t stream)
{
    const float* spatial  = (const float*)d_in[0];
    const float* gfeat    = (const float*)d_in[1];
    const int*   caps     = (const int*)d_in[2];
    const int*   lengths  = (const int*)d_in[3];
    const float* emb      = (const float*)d_in[4];
    const float* W_init_h = (const float*)d_in[5];
    const float* b_init_h = (const float*)d_in[6];
    const float* W_init_m = (const float*)d_in[7];
    const float* b_init_m = (const float*)d_in[8];
    const float* W_ih     = (const float*)d_in[9];
    const float* b_ih     = (const float*)d_in[10];
    const float* W_hh     = (const float*)d_in[11];
    const float* b_hh     = (const float*)d_in[12];
    const float* Wv       = (const float*)d_in[13];
    const float* bv       = (const float*)d_in[14];
    const float* Wg       = (const float*)d_in[15];
    const float* bg       = (const float*)d_in[16];
    const float* wh       = (const float*)d_in[17];
    const float* bh_att   = (const float*)d_in[18];
    const float* Wp       = (const float*)d_in[19];
    const float* bp       = (const float*)d_in[20];
    float* out = (float*)d_out;
    (void)bh_att;

    char* ws = (char*)d_ws;
    size_t off = 0;
    auto alloc = [&](size_t bytes) -> void* {
        off = (off + 255) & ~(size_t)255;
        void* p = ws + off;
        off += bytes;
        return p;
    };

    bf16* Wp_b    = (bf16*)alloc((size_t)VPAD * D_ * 2);
    bf16* Whh_b   = (bf16*)alloc((size_t)NG_ * D_ * 2);
    bf16* Wih_b   = (bf16*)alloc((size_t)NG_ * XK_ * 2);
    bf16* Xin_b   = (bf16*)alloc((size_t)T_ * B_ * XK_ * 2);
    bf16* Sp_b    = (bf16*)alloc((size_t)B_ * KK_ * D_ * 2);
    bf16* Wv_b    = (bf16*)alloc((size_t)NP_ * D_ * 2);
    bf16* Wg_b    = (bf16*)alloc((size_t)NP_ * D_ * 2);
    bf16* Winit2_b= (bf16*)alloc((size_t)2 * D_ * D_ * 2);
    bf16* Gf_b    = (bf16*)alloc((size_t)B_ * D_ * 2);
    float* bias_comb = (float*)alloc(NG_ * 4);
    float* bias_init = (float*)alloc(2 * D_ * 4);
    float* bv_pad    = (float*)alloc(NP_ * 4);
    float* bg_pad    = (float*)alloc(NP_ * 4);
    bf16* Hb16    = (bf16*)alloc((size_t)(T_ + 1) * B_ * D_ * 2);
    float* mbuf   = (float*)alloc((size_t)B_ * D_ * 4);
    float* Xpre   = (float*)alloc((size_t)T_ * B_ * NG_ * 4);
    float* VprojW = (float*)alloc((size_t)B_ * KK_ * NP_ * 4);
    float* g_allW = (float*)alloc((size_t)T_ * B_ * NP_ * 4);
    bf16* ctx     = (bf16*)alloc((size_t)T_ * B_ * D_ * 2);
    int*  flags   = (int*)alloc((size_t)NBLK * 32 * 4);

    // 1. prep / conversions / flag zeroing
    prep_kernel<<<1024, 256, 0, stream>>>(
        spatial, gfeat, caps, emb, W_init_h, b_init_h, W_init_m, b_init_m,
        W_ih, b_ih, W_hh, b_hh, Wv, bv, Wg, bg, Wp,
        Wp_b, Whh_b, Wih_b, Xin_b, Sp_b, Wv_b, Wg_b, Winit2_b, Gf_b,
        bias_comb, bias_init, bv_pad, bg_pad, flags);

    // 2. h0 (bf16 -> Hb16[0]) and m0 (f32 -> mbuf) in one GEMM
    gemm_bt<3><<<dim3(1, 8), 256, 0, stream>>>(Gf_b, Winit2_b, bias_init,
                                               Hb16, mbuf, B_, 2 * D_, D_, 0, 0, nullptr);

    // 3. V_proj = spatial @ Wv^T + bv  -> [B*K, 128] f32
    gemm_bt<0><<<dim3((B_ * KK_) / 128, 1), 256, 0, stream>>>(
        Sp_b, Wv_b, bv_pad, VprojW, nullptr, B_ * KK_, NP_, D_, NP_, 0, nullptr);

    // 4. Xpre = Xin @ W_ih^T + (b_ih + b_hh)  -> [T*B, 2048] f32
    gemm_bt<0><<<dim3((T_ * B_) / 128, NG_ / 128), 256, 0, stream>>>(
        Xin_b, Wih_b, bias_comb, Xpre, nullptr, T_ * B_, NG_, XK_, NG_, 0, nullptr);

    // 5. all 20 LSTM steps: ONE persistent kernel, XCD-local runner group
    lstm_persist<<<LGRID, 256, 0, stream>>>(Hb16, Whh_b, Xpre, mbuf, lengths, flags);

    // 6. g_all = H[1..T] @ Wg^T + bg  -> [T*B, 128] f32
    gemm_bt<0><<<dim3((T_ * B_) / 128, 1), 256, 0, stream>>>(
        Hb16 + (size_t)B_ * D_, Wg_b, bg_pad, g_allW, nullptr, T_ * B_, NP_, D_, NP_, 0, nullptr);

    // 7. attention + ctx = c + h  (bf16, rows b*T+t)
    attn_kernel<<<B_ * 5, 256, 0, stream>>>(Hb16, g_allW, VprojW, wh, Sp_b, ctx);

    // 8. logits = ctx @ Wp^T + bp, masked, -> d_out [B*T, V]
    gemm_bt<2><<<dim3((T_ * B_) / 128, VPAD / 128), 256, 0, stream>>>(
        ctx, Wp_b, bp, out, nullptr, T_ * B_, VPAD, D_, V_, V_, lengths);
}